// Round 4
// baseline (25.410 us; speedup 1.0000x reference)
//
#include <hip/hip_runtime.h>

#define HH 128
#define WW 128
#define CC 3
#define TX 16
#define TY 8
#define NPIX 128              // TX*TY
#define TC 26                 // used img-tile cols (TX+10)
#define TR 18                 // img-tile rows (TY+10)
#define TSTR 48               // padded row stride: 16y+x bank map -> 2-way (free)
#define SW 20                 // stats cols (TX+4)
#define SH 12                 // stats rows (TY+4)
#define NST (SW*SH)           // 240
#define PSTRIDE 25            // odd stride -> 2-way LDS aliasing
#define NTHR 768              // 128 px * 3 ch * 2 neighbor-halves

__global__ void __launch_bounds__(NTHR)
__attribute__((amdgpu_waves_per_eu(2, 3)))   // max 3 waves/EU: forbid the VGPR squeeze that spilled R3
err_neurons_kernel(const float* __restrict__ img, float* __restrict__ out) {
    __shared__ float s_img[CC][TR][TSTR];
    __shared__ float s_rs[CC][TR][SW];    // 7-wide row sums
    __shared__ float s_rs2[CC][TR][SW];   // 7-wide row sums of squares
    __shared__ float s_mu[CC][NST];
    __shared__ float s_r[CC][NST];
    __shared__ float s_nsq[CC][NST];
    __shared__ float s_rnrm[NST];
    __shared__ float s_part[CC][NPIX * PSTRIDE];

    const int tid = threadIdx.x;
    const int x0 = blockIdx.x * TX, y0 = blockIdx.y * TY;
    const float* imgb = img + (size_t)blockIdx.z * CC * HH * WW;

    // ---- Phase 1: stage zero-padded 18x26 tiles, 3 channels ----
    for (int i = tid; i < CC * TR * TC; i += NTHR) {
        const int c = i / (TR * TC), r = i % (TR * TC);
        const int iy = r / TC, ix = r % TC;
        const int yy = y0 - 5 + iy, xx = x0 - 5 + ix;
        float v = 0.f;
        if ((unsigned)yy < HH && (unsigned)xx < WW)
            v = imgb[(size_t)c * HH * WW + yy * WW + xx];
        s_img[c][iy][ix] = v;
    }
    __syncthreads();

    // ---- Phase 2a: separable stats, horizontal 7-wide sums ----
    for (int u2 = tid; u2 < CC * TR * SW; u2 += NTHR) {
        const int c = u2 / (TR * SW);
        const int rem = u2 % (TR * SW);
        const int r = rem / SW, sx = rem % SW;
        const float* bp = &s_img[c][r][sx];
        float s = 0.f, s2 = 0.f;
#pragma unroll
        for (int j = 0; j < 7; ++j) { float v = bp[j]; s += v; s2 = fmaf(v, v, s2); }
        s_rs[c][r][sx] = s; s_rs2[c][r][sx] = s2;
    }
    __syncthreads();

    // ---- Phase 2b: vertical 7-tall sums -> mu, rsqrt(var+eps), ||f_c||^2 ----
    for (int u2 = tid; u2 < CC * NST; u2 += NTHR) {
        const int c = u2 / NST;
        const int pos = u2 % NST;
        const int sy = pos / SW, sx = pos % SW;
        float s = 0.f, s2 = 0.f;
#pragma unroll
        for (int i = 0; i < 7; ++i) { s += s_rs[c][sy + i][sx]; s2 += s_rs2[c][sy + i][sx]; }
        const float mu  = s * (1.f / 49.f);
        const float var = fmaxf(fmaf(-mu, mu, s2 * (1.f / 49.f)), 0.f);
        const float rr  = rsqrtf(var + 1e-5f);
        s_mu[c][pos] = mu;
        s_r[c][pos]  = rr;
        s_nsq[c][pos] = fmaf(49.f * var, rr * rr, 196.f);
    }
    __syncthreads();
    if (tid < NST)
        s_rnrm[tid] = rsqrtf(s_nsq[0][tid] + s_nsq[1][tid] + s_nsq[2][tid]);
    __syncthreads();

    // ---- Phase 3: cross-correlations; thread = (pixel, channel, nb-half) ----
    {
        const int p = tid & 127;
        const int g = tid >> 7;          // uniform per wave-pair
        const int c = g % 3, h = g / 3;  // h = neighbor half
        const int x = p & 15, y = p >> 4;
        const int row0 = y + 2 * h;      // window base row in s_img
        float W[9][11];
#pragma unroll
        for (int r = 0; r < 9; ++r)
#pragma unroll
            for (int q = 0; q < 11; ++q)
                W[r][q] = s_img[c][row0 + r][x + q];
        const int spos = (y + 2) * SW + (x + 2);
        const float mut = s_mu[c][spos];
        const float rt  = s_r[c][spos];
        float* partp = &s_part[c][p * PSTRIDE];
        if (h == 0) {
            // neighbors u = 0..11 (dy in {-2,-1,0-}); W rows = tile rows y-5..y+3
#pragma unroll
            for (int j = 0; j < 12; ++j) {
                const int dy = j / 5 - 2, dx = j % 5 - 2;
                float cross = 0.f;
#pragma unroll
                for (int oy = 0; oy < 7; ++oy)
#pragma unroll
                    for (int ox = 0; ox < 7; ++ox)
                        cross = fmaf(W[2 + oy][2 + ox], W[2 + dy + oy][2 + dx + ox], cross);
                const int upos = (y + 2 + dy) * SW + (x + 2 + dx);
                partp[j] = fmaf(-49.f * mut, s_mu[c][upos], cross) * (rt * s_r[c][upos]);
            }
        } else {
            // neighbors u = 13..24 (dy in {0+,1,2}); W rows = tile rows y-3..y+5
#pragma unroll
            for (int j = 0; j < 12; ++j) {
                const int u = j + 13;
                const int dy = u / 5 - 2, dx = u % 5 - 2;
                float cross = 0.f;
#pragma unroll
                for (int oy = 0; oy < 7; ++oy)
#pragma unroll
                    for (int ox = 0; ox < 7; ++ox)
                        cross = fmaf(W[oy][2 + ox], W[dy + oy][2 + dx + ox], cross);
                const int upos = (y + 2 + dy) * SW + (x + 2 + dx);
                partp[j + 12] = fmaf(-49.f * mut, s_mu[c][upos], cross) * (rt * s_r[c][upos]);
            }
        }
    }
    __syncthreads();

    // ---- Phase 4: combine channels, cosine, masked mean ----
    if (tid < NPIX) {
        const int p = tid, x = p & 15, y = p >> 4;
        const int gx = x0 + x, gy = y0 + y;
        const float rnt = s_rnrm[(y + 2) * SW + (x + 2)];
        float csum = 0.f, cnt = 0.f;
#pragma unroll
        for (int u = 0; u < 25; ++u) {
            if (u == 12) continue;
            const int dy = u / 5 - 2, dx = u % 5 - 2;
            const int j = u - (u > 12 ? 1 : 0);
            if ((unsigned)(gy + dy) >= HH || (unsigned)(gx + dx) >= WW) continue;
            const float dot = 588.f + s_part[0][p * PSTRIDE + j]
                                    + s_part[1][p * PSTRIDE + j]
                                    + s_part[2][p * PSTRIDE + j];
            csum += dot * rnt * s_rnrm[(y + 2 + dy) * SW + (x + 2 + dx)];
            cnt += 1.f;
        }
        out[(size_t)blockIdx.z * HH * WW + gy * WW + gx] = 0.5f - csum / (2.f * cnt);
    }
}

extern "C" void kernel_launch(void* const* d_in, const int* in_sizes, int n_in,
                              void* d_out, int out_size, void* d_ws, size_t ws_size,
                              hipStream_t stream) {
    const float* img = (const float*)d_in[0];
    float* out = (float*)d_out;
    dim3 grid(WW / TX, HH / TY, 2);
    dim3 block(NTHR);
    hipLaunchKernelGGL(err_neurons_kernel, grid, block, 0, stream, img, out);
}

// Round 5
// 14.864 us; speedup vs baseline: 1.7095x; 1.7095x over previous
//
#include <hip/hip_runtime.h>

#define HH 128
#define WW 128
#define TX 8
#define TY 8
#define IR 22        // img tile rows/cols: offsets -7..14
#define ISTR 25      // img row stride (odd -> bank-spread)
#define S4 16        // stats region: -4..11
#define S4S 17
#define S2 12        // part/B region: -2..9
#define S2S 13
#define PR 18        // product rows: -5..12
#define NTHR 256

__global__ void __launch_bounds__(NTHR)
err_kernel(const float* __restrict__ img, float* __restrict__ out) {
    __shared__ float s_img[3][IR][ISTR];
    __shared__ union U1 {
        float rs[2][3][IR][S4S];   // [sum|sum2][c][img-row][s4col] (phase 2)
        float H[36][PR][S2];       // [d*3+c][prow][s2col]          (phase 3)
    } u1;
    __shared__ float s_mu[3][S4][S4S];
    __shared__ float s_r [3][S4][S4S];
    __shared__ union U2 {
        float nsq[3][S2][S2S];     // phase 2 only
        float part[12][S2][S2S];   // phase 3c+
    } u2;
    __shared__ float s_rnrm[S2][S2S];
    __shared__ float s_B[12][3][S2][S2S];
    __shared__ float s_red[2][4][64];

    const int tid = threadIdx.x;
    const int x0 = blockIdx.x * TX, y0 = blockIdx.y * TY;
    const float* imgb = img + (size_t)blockIdx.z * 3 * HH * WW;

    // ---- P1: stage zero-padded 22x22 tiles (origin -7,-7), 3 channels ----
    for (int i = tid; i < 3 * IR * IR; i += NTHR) {
        const int c = i / (IR * IR);
        const int rem = i - c * IR * IR;
        const int iy = rem / IR, ix = rem - iy * IR;
        const int yy = y0 - 7 + iy, xx = x0 - 7 + ix;
        float v = 0.f;
        if ((unsigned)yy < HH && (unsigned)xx < WW)
            v = imgb[c * HH * WW + yy * WW + xx];
        s_img[c][iy][ix] = v;
    }
    __syncthreads();

    // ---- P2a: horizontal 7-sums of I and I^2 (sliding), task=(c,row) ----
    if (tid < 66) {
        const int c = tid / 22, row = tid - c * 22;
        float f[22];
#pragma unroll
        for (int j = 0; j < 22; ++j) f[j] = s_img[c][row][j];
        float s = 0.f, s2 = 0.f;
#pragma unroll
        for (int k = 0; k < 7; ++k) { s += f[k]; s2 = fmaf(f[k], f[k], s2); }
        u1.rs[0][c][row][0] = s; u1.rs[1][c][row][0] = s2;
#pragma unroll
        for (int x = 1; x < S4; ++x) {
            s += f[x + 6] - f[x - 1];
            s2 += fmaf(f[x + 6], f[x + 6], -f[x - 1] * f[x - 1]);
            u1.rs[0][c][row][x] = s; u1.rs[1][c][row][x] = s2;
        }
    }
    __syncthreads();

    // ---- P2b: vertical 7-sums -> mu, r, nsq; task=(c,col,half) ----
    if (tid < 96) {
        const int c = tid / 32;
        const int rem = tid - c * 32;
        const int col = rem >> 1, h = rem & 1;
        const int r0 = h * 8;
        float s = 0.f, s2 = 0.f;
#pragma unroll
        for (int k = 0; k < 7; ++k) { s += u1.rs[0][c][r0 + k][col]; s2 += u1.rs[1][c][r0 + k][col]; }
#pragma unroll
        for (int i = 0; i < 8; ++i) {
            const int rr4 = r0 + i;
            const float mu  = s * (1.f / 49.f);
            const float var = fmaxf(fmaf(-mu, mu, s2 * (1.f / 49.f)), 0.f);
            const float rv  = rsqrtf(var + 1e-5f);
            s_mu[c][rr4][col] = mu;
            s_r [c][rr4][col] = rv;
            const int sr = rr4 - 2, sc = col - 2;
            if ((unsigned)sr < S2 && (unsigned)sc < S2)
                u2.nsq[c][sr][sc] = fmaf(49.f * var, rv * rv, 196.f);
            if (i < 7) {
                s  += u1.rs[0][c][rr4 + 7][col] - u1.rs[0][c][rr4][col];
                s2 += u1.rs[1][c][rr4 + 7][col] - u1.rs[1][c][rr4][col];
            }
        }
    }
    __syncthreads();

    // ---- P2c (first 144 thr) + P3a (all): rnrm  ||  product row-sums H ----
    if (tid < 144) {
        const int py = tid / 12, px = tid - py * 12;
        s_rnrm[py][px] = rsqrtf(u2.nsq[0][py][px] + u2.nsq[1][py][px] + u2.nsq[2][py][px]);
    }
    // H: task=(d,c,prow); P_j folded in. 648 tasks.
    for (int q = tid; q < 648; q += NTHR) {
        const int cd = q / 18;
        const int prow = q - cd * 18;
        const int dI = cd / 3, c = cd - dI * 3;
        const int u = dI + 13;
        const int dy = u / 5 - 2, dx = u - (u / 5) * 5 - 2;
        const float* rowA = &s_img[c][prow + 2][2];
        const float* rowB = &s_img[c][prow + 2 + dy][2 + dx];
        float P[18];
#pragma unroll
        for (int j = 0; j < 18; ++j) P[j] = rowA[j] * rowB[j];
        float hsum = P[0] + P[1] + P[2] + P[3] + P[4] + P[5] + P[6];
        u1.H[cd][prow][0] = hsum;
#pragma unroll
        for (int j = 1; j < S2; ++j) { hsum += P[j + 6] - P[j - 1]; u1.H[cd][prow][j] = hsum; }
    }
    __syncthreads();

    // ---- P3b: vertical 7-sums of H -> B; task=(d,c,col). 432 tasks ----
    for (int q = tid; q < 432; q += NTHR) {
        const int cd = q / 12, col = q - cd * 12;
        const int dI = cd / 3, c = cd - dI * 3;
        float b = 0.f;
#pragma unroll
        for (int k = 0; k < 7; ++k) b += u1.H[cd][k][col];
        s_B[dI][c][0][col] = b;
#pragma unroll
        for (int r2 = 1; r2 < S2; ++r2) {
            b += u1.H[cd][r2 + 6][col] - u1.H[cd][r2 - 1][col];
            s_B[dI][c][r2][col] = b;
        }
    }
    __syncthreads();

    // ---- P3c: part[d][t'] = sum_c (B - 49 mu mu) r r ; 1728 tasks ----
    for (int q = tid; q < 1728; q += NTHR) {
        const int dI = q / 144;
        const int pos = q - dI * 144;
        const int py = pos / 12, px = pos - py * 12;
        const int u = dI + 13;
        const int dy = u / 5 - 2, dx = u - (u / 5) * 5 - 2;
        const int r1 = py + 2, c1 = px + 2;
        const int r2 = r1 + dy, c2 = c1 + dx;
        float acc = 0.f;
#pragma unroll
        for (int c = 0; c < 3; ++c) {
            const float m = s_mu[c][r1][c1] * s_mu[c][r2][c2];
            const float v = fmaf(-49.f, m, s_B[dI][c][py][px]);
            acc = fmaf(v, s_r[c][r1][c1] * s_r[c][r2][c2], acc);
        }
        u2.part[dI][py][px] = acc;
    }
    __syncthreads();

    // ---- P4: per-pixel cosine accumulation; thread=(pixel, quarter) ----
    {
        const int p = tid & 63, quarter = tid >> 6;   // quarter wave-uniform
        const int ty = p >> 3, tx = p & 7;
        const int gy = y0 + ty, gx = x0 + tx;
        float acc = 0.f, cnt = 0.f;
#pragma unroll
        for (int j = 0; j < 3; ++j) {
            const int dI = quarter * 3 + j;
            const int u = dI + 13;
            const int dy = u / 5 - 2, dx = u - (u / 5) * 5 - 2;
            if ((unsigned)(gy + dy) < HH && (unsigned)(gx + dx) < WW) {
                const float ps = u2.part[dI][ty + 2][tx + 2];
                acc = fmaf(588.f + ps, s_rnrm[ty + 2 + dy][tx + 2 + dx], acc);
                cnt += 1.f;
            }
            if ((unsigned)(gy - dy) < HH && (unsigned)(gx - dx) < WW) {
                const float ps = u2.part[dI][ty + 2 - dy][tx + 2 - dx];
                acc = fmaf(588.f + ps, s_rnrm[ty + 2 - dy][tx + 2 - dx], acc);
                cnt += 1.f;
            }
        }
        s_red[0][quarter][p] = acc;
        s_red[1][quarter][p] = cnt;
    }
    __syncthreads();
    if (tid < 64) {
        const int ty = tid >> 3, tx = tid & 7;
        const float a = s_red[0][0][tid] + s_red[0][1][tid] + s_red[0][2][tid] + s_red[0][3][tid];
        const float n = s_red[1][0][tid] + s_red[1][1][tid] + s_red[1][2][tid] + s_red[1][3][tid];
        const float rn = s_rnrm[ty + 2][tx + 2];
        out[(size_t)blockIdx.z * HH * WW + (y0 + ty) * WW + (x0 + tx)] =
            0.5f - a * rn / (2.f * n);
    }
}

extern "C" void kernel_launch(void* const* d_in, const int* in_sizes, int n_in,
                              void* d_out, int out_size, void* d_ws, size_t ws_size,
                              hipStream_t stream) {
    const float* img = (const float*)d_in[0];
    float* out = (float*)d_out;
    dim3 grid(WW / TX, HH / TY, 2);
    dim3 block(NTHR);
    hipLaunchKernelGGL(err_kernel, grid, block, 0, stream, img, out);
}

// Round 6
// 14.382 us; speedup vs baseline: 1.7668x; 1.0335x over previous
//
#include <hip/hip_runtime.h>

#define HH 128
#define WW 128
#define TX 8
#define TY 8
#define IR 22        // img tile rows/cols: image offsets -7..14
#define ISTR 23      // odd row stride -> bank spread
#define S4 16        // stats region: -4..11
#define S4S 17
#define S2 12        // part region: -2..9
#define S2S 13
#define NTHR 256

__global__ void __launch_bounds__(NTHR)
err_kernel(const float* __restrict__ img, float* __restrict__ out) {
    __shared__ float s_img[3][IR][ISTR];
    __shared__ union U1 {
        float rs[2][3][IR][S4S];   // [sum|sum2][c][img-row][x]  (phase 2)
        float H[36][18][S2];       // [d*3+c][prow][x]           (phase 3)
    } u1;
    __shared__ float s_mu[3][S4][S4S];
    __shared__ float s_r [3][S4][S4S];
    __shared__ union U2 {
        float nsq[3][S2][S2S];     // phase 2 only
        float part[12][S2][S2S];   // phase 3+
    } u2;
    __shared__ float s_rnrm[S2][S2S];

    const int tid = threadIdx.x;
    const int x0 = blockIdx.x * TX, y0 = blockIdx.y * TY;
    const float* imgb = img + (size_t)blockIdx.z * 3 * HH * WW;

    // ---- P1: stage zero-padded 22x22 tiles (origin -7,-7), 3 channels ----
    for (int i = tid; i < 3 * IR * IR; i += NTHR) {
        const int c = i / (IR * IR);
        const int rem = i - c * IR * IR;
        const int iy = rem / IR, ix = rem - iy * IR;
        const int yy = y0 - 7 + iy, xx = x0 - 7 + ix;
        float v = 0.f;
        if ((unsigned)yy < HH && (unsigned)xx < WW)
            v = imgb[c * HH * WW + yy * WW + xx];
        s_img[c][iy][ix] = v;
    }
    __syncthreads();

    // ---- P2a: horizontal 7-sums of I and I^2 (sliding); task=(c,row) ----
    if (tid < 66) {
        const int c = tid / 22, row = tid - c * 22;
        float f[22];
#pragma unroll
        for (int j = 0; j < 22; ++j) f[j] = s_img[c][row][j];
        float s = 0.f, s2 = 0.f;
#pragma unroll
        for (int k = 0; k < 7; ++k) { s += f[k]; s2 = fmaf(f[k], f[k], s2); }
        u1.rs[0][c][row][0] = s; u1.rs[1][c][row][0] = s2;
#pragma unroll
        for (int x = 1; x < S4; ++x) {
            s += f[x + 6] - f[x - 1];
            s2 += fmaf(f[x + 6], f[x + 6], -f[x - 1] * f[x - 1]);
            u1.rs[0][c][row][x] = s; u1.rs[1][c][row][x] = s2;
        }
    }
    __syncthreads();

    // ---- P2b: vertical 7-sums -> mu, r, nsq; task=(c,col,half) ----
    if (tid < 96) {
        const int c = tid / 32;
        const int rem = tid - c * 32;
        const int col = rem >> 1, h = rem & 1;
        const int r0 = h * 8;
        float s = 0.f, s2 = 0.f;
#pragma unroll
        for (int k = 0; k < 7; ++k) { s += u1.rs[0][c][r0 + k][col]; s2 += u1.rs[1][c][r0 + k][col]; }
#pragma unroll
        for (int i = 0; i < 8; ++i) {
            const int rr4 = r0 + i;
            const float mu  = s * (1.f / 49.f);
            const float var = fmaxf(fmaf(-mu, mu, s2 * (1.f / 49.f)), 0.f);
            const float rv  = rsqrtf(var + 1e-5f);
            s_mu[c][rr4][col] = mu;
            s_r [c][rr4][col] = rv;
            const int sr = rr4 - 2, sc = col - 2;
            if ((unsigned)sr < S2 && (unsigned)sc < S2)
                u2.nsq[c][sr][sc] = fmaf(49.f * var, rv * rv, 196.f);
            if (i < 7) {
                s  += u1.rs[0][c][rr4 + 7][col] - u1.rs[0][c][rr4][col];
                s2 += u1.rs[1][c][rr4 + 7][col] - u1.rs[1][c][rr4][col];
            }
        }
    }
    __syncthreads();

    // ---- P3a: rnrm (144 thr)  ||  product row-sums H (648 tasks) ----
    if (tid < 144) {
        const int py = tid / 12, px = tid - py * 12;
        s_rnrm[py][px] = rsqrtf(u2.nsq[0][py][px] + u2.nsq[1][py][px] + u2.nsq[2][py][px]);
    }
    for (int q = tid; q < 648; q += NTHR) {
        const int cd = q / 18;
        const int prow = q - cd * 18;
        const int dI = cd / 3, c = cd - dI * 3;
        const int u = dI + 13;
        const int dy = u / 5 - 2, dx = u - (u / 5) * 5 - 2;
        const float* rowA = &s_img[c][prow + 2][2];
        const float* rowB = &s_img[c][prow + 2 + dy][2 + dx];
        float P[18];
#pragma unroll
        for (int j = 0; j < 18; ++j) P[j] = rowA[j] * rowB[j];
        float hsum = P[0] + P[1] + P[2] + P[3] + P[4] + P[5] + P[6];
        u1.H[cd][prow][0] = hsum;
#pragma unroll
        for (int j = 1; j < S2; ++j) { hsum += P[j + 6] - P[j - 1]; u1.H[cd][prow][j] = hsum; }
    }
    __syncthreads();

    // ---- P3b: vertical slide of H + channel-combine -> part; 144 thr ----
    if (tid < 144) {
        const int dI = tid / 12, col = tid - dI * 12;
        const int u = dI + 13;
        const int dy = u / 5 - 2, dx = u - (u / 5) * 5 - 2;
        float B[3];
#pragma unroll
        for (int c = 0; c < 3; ++c) {
            float b = 0.f;
#pragma unroll
            for (int k = 0; k < 7; ++k) b += u1.H[dI * 3 + c][k][col];
            B[c] = b;
        }
#pragma unroll
        for (int y = 0; y < S2; ++y) {
            float acc = 0.f;
#pragma unroll
            for (int c = 0; c < 3; ++c) {
                const float m = s_mu[c][y + 2][col + 2] * s_mu[c][y + 2 + dy][col + 2 + dx];
                const float v = fmaf(-49.f, m, B[c]);
                acc = fmaf(v, s_r[c][y + 2][col + 2] * s_r[c][y + 2 + dy][col + 2 + dx], acc);
            }
            u2.part[dI][y][col] = acc;
            if (y < S2 - 1) {
#pragma unroll
                for (int c = 0; c < 3; ++c)
                    B[c] += u1.H[dI * 3 + c][y + 7][col] - u1.H[dI * 3 + c][y][col];
            }
        }
    }
    __syncthreads();

    // ---- P4: per-pixel cosine accumulation, direct store; 64 thr ----
    if (tid < 64) {
        const int ty = tid >> 3, tx = tid & 7;
        const int gy = y0 + ty, gx = x0 + tx;
        const float rnt = s_rnrm[ty + 2][tx + 2];
        float acc = 0.f, cnt = 0.f;
#pragma unroll
        for (int dI = 0; dI < 12; ++dI) {
            const int u = dI + 13;
            const int dy = u / 5 - 2, dx = u - (u / 5) * 5 - 2;
            if ((unsigned)(gy + dy) < HH && (unsigned)(gx + dx) < WW) {
                const float ps = u2.part[dI][ty + 2][tx + 2];
                acc = fmaf(588.f + ps, s_rnrm[ty + 2 + dy][tx + 2 + dx], acc);
                cnt += 1.f;
            }
            if ((unsigned)(gy - dy) < HH && (unsigned)(gx - dx) < WW) {
                const float ps = u2.part[dI][ty + 2 - dy][tx + 2 - dx];
                acc = fmaf(588.f + ps, s_rnrm[ty + 2 - dy][tx + 2 - dx], acc);
                cnt += 1.f;
            }
        }
        out[(size_t)blockIdx.z * HH * WW + gy * WW + gx] = 0.5f - acc * rnt / (2.f * cnt);
    }
}

extern "C" void kernel_launch(void* const* d_in, const int* in_sizes, int n_in,
                              void* d_out, int out_size, void* d_ws, size_t ws_size,
                              hipStream_t stream) {
    const float* img = (const float*)d_in[0];
    float* out = (float*)d_out;
    dim3 grid(WW / TX, HH / TY, 2);
    dim3 block(NTHR);
    hipLaunchKernelGGL(err_kernel, grid, block, 0, stream, img, out);
}

// Round 7
// 14.366 us; speedup vs baseline: 1.7687x; 1.0011x over previous
//
#include <hip/hip_runtime.h>

#define HH 128
#define WW 128
#define TX 8
#define TY 8
#define IR 22        // img tile rows: offsets -7..14
#define ISTR 28      // row stride: 16B-aligned (28*4=112B), 8-way bank spread
#define NTHR 256

__global__ void __launch_bounds__(NTHR)
err_kernel(const float* __restrict__ img, float* __restrict__ out) {
    __shared__ float s_img[3][IR][ISTR];            // 7392 B
    __shared__ union U1 {
        float rs[2][3][IR][17];                     // stats row-sums (P2)
        float H[36][18][12];                        // product h-sums (P3), 48B rows
    } u1;                                           // 31104 B
    __shared__ float s_stat[16][16][8];             // [r0 r1 r2 _ | a0 a1 a2 _], 8192 B
    __shared__ union U2 {
        float nsq[3][12][12];
        float part[12][12][12];
    } u2;                                           // 6912 B
    __shared__ float s_rnrm[12][12];                // 576 B

    const int tid = threadIdx.x;
    const int x0 = blockIdx.x * TX, y0 = blockIdx.y * TY;
    const float* imgb = img + (size_t)blockIdx.z * 3 * HH * WW;

    // ---- P1: stage zero-padded 22x28 rows (origin -7,-7), 3 channels ----
    for (int i = tid; i < 3 * IR * ISTR; i += NTHR) {
        const int c = i / (IR * ISTR);
        const int rem = i - c * IR * ISTR;
        const int iy = rem / ISTR, ix = rem - iy * ISTR;
        const int yy = y0 - 7 + iy, xx = x0 - 7 + ix;
        float v = 0.f;
        if ((unsigned)yy < HH && (unsigned)xx < WW)
            v = imgb[c * HH * WW + yy * WW + xx];
        s_img[c][iy][ix] = v;
    }
    __syncthreads();

    // ---- P2a: horizontal 7-sums of I, I^2 (sliding); task=(c,row), 66 ----
    if (tid < 66) {
        const int c = tid / 22, row = tid - c * 22;
        float f[24];
        const float4* rp = (const float4*)&s_img[c][row][0];
#pragma unroll
        for (int q = 0; q < 6; ++q) ((float4*)f)[q] = rp[q];
        float s = 0.f, s2 = 0.f;
#pragma unroll
        for (int k = 0; k < 7; ++k) { s += f[k]; s2 = fmaf(f[k], f[k], s2); }
        u1.rs[0][c][row][0] = s; u1.rs[1][c][row][0] = s2;
#pragma unroll
        for (int x = 1; x < 16; ++x) {
            s += f[x + 6] - f[x - 1];
            s2 += fmaf(f[x + 6], f[x + 6], -f[x - 1] * f[x - 1]);
            u1.rs[0][c][row][x] = s; u1.rs[1][c][row][x] = s2;
        }
    }
    __syncthreads();

    // ---- P2b: vertical 7-sums -> packed (r, a=mu*r), nsq; 96 thr ----
    if (tid < 96) {
        const int c = tid / 32;
        const int rem = tid - c * 32;
        const int col = rem >> 1, h2 = rem & 1;
        const int r0 = h2 * 8;
        float s = 0.f, s2 = 0.f;
#pragma unroll
        for (int k = 0; k < 7; ++k) { s += u1.rs[0][c][r0 + k][col]; s2 += u1.rs[1][c][r0 + k][col]; }
#pragma unroll
        for (int i = 0; i < 8; ++i) {
            const int rr4 = r0 + i;
            const float mu  = s * (1.f / 49.f);
            const float var = fmaxf(fmaf(-mu, mu, s2 * (1.f / 49.f)), 0.f);
            const float rv  = rsqrtf(var + 1e-5f);
            s_stat[rr4][col][c]     = rv;
            s_stat[rr4][col][4 + c] = mu * rv;
            const int sr = rr4 - 2, sc = col - 2;
            if ((unsigned)sr < 12 && (unsigned)sc < 12)
                u2.nsq[c][sr][sc] = fmaf(49.f * var, rv * rv, 196.f);
            if (i < 7) {
                s  += u1.rs[0][c][rr4 + 7][col] - u1.rs[0][c][rr4][col];
                s2 += u1.rs[1][c][rr4 + 7][col] - u1.rs[1][c][rr4][col];
            }
        }
    }
    __syncthreads();

    // ---- P3a: rnrm (144 thr)  ||  product h-sums, rowB shared per dy (162 thr) ----
    if (tid < 144) {
        const int py = tid / 12, px = tid - py * 12;
        s_rnrm[py][px] = rsqrtf(u2.nsq[0][py][px] + u2.nsq[1][py][px] + u2.nsq[2][py][px]);
    }
    if (tid < 162) {
        const int dy = tid / 54;
        const int rem = tid - dy * 54;
        const int c = rem / 18, prow = rem - c * 18;
        float rA[24], rB[24];
        const float4* pA = (const float4*)&s_img[c][prow + 2][0];
        const float4* pB = (const float4*)&s_img[c][prow + 2 + dy][0];
#pragma unroll
        for (int q = 0; q < 6; ++q) { ((float4*)rA)[q] = pA[q]; ((float4*)rB)[q] = pB[q]; }

#define EMIT(dI, dx) do {                                                   \
        float P[18];                                                        \
        _Pragma("unroll")                                                   \
        for (int j = 0; j < 18; ++j) P[j] = rA[j + 2] * rB[j + 2 + (dx)];   \
        float w[12];                                                        \
        float h = P[0]+P[1]+P[2]+P[3]+P[4]+P[5]+P[6];                       \
        w[0] = h;                                                           \
        _Pragma("unroll")                                                   \
        for (int j = 1; j < 12; ++j) { h += P[j + 6] - P[j - 1]; w[j] = h; }\
        float4* wp = (float4*)&u1.H[(dI) * 3 + c][prow][0];                 \
        wp[0] = make_float4(w[0], w[1], w[2],  w[3]);                       \
        wp[1] = make_float4(w[4], w[5], w[6],  w[7]);                       \
        wp[2] = make_float4(w[8], w[9], w[10], w[11]);                      \
    } while (0)

        if (dy == 0)      { EMIT(0, 1); EMIT(1, 2); }
        else if (dy == 1) { EMIT(2, -2); EMIT(3, -1); EMIT(4, 0); EMIT(5, 1); EMIT(6, 2); }
        else              { EMIT(7, -2); EMIT(8, -1); EMIT(9, 0); EMIT(10, 1); EMIT(11, 2); }
#undef EMIT
    }
    __syncthreads();

    // ---- P3b: vertical slide of H (in regs) + packed-stat combine -> part ----
    if (tid < 144) {
        const int dI = tid / 12, col = tid - dI * 12;
        const int u = dI + 13;
        const int dy = u / 5 - 2, dx = u - (u / 5) * 5 - 2;
        float h[3][18];
#pragma unroll
        for (int c = 0; c < 3; ++c)
#pragma unroll
            for (int k = 0; k < 18; ++k) h[c][k] = u1.H[dI * 3 + c][k][col];
        float B0 = h[0][0]+h[0][1]+h[0][2]+h[0][3]+h[0][4]+h[0][5]+h[0][6];
        float B1 = h[1][0]+h[1][1]+h[1][2]+h[1][3]+h[1][4]+h[1][5]+h[1][6];
        float B2 = h[2][0]+h[2][1]+h[2][2]+h[2][3]+h[2][4]+h[2][5]+h[2][6];
#pragma unroll
        for (int y = 0; y < 12; ++y) {
            const float4 t1 = *(const float4*)&s_stat[y + 2][col + 2][0];
            const float4 t2 = *(const float4*)&s_stat[y + 2][col + 2][4];
            const float4 n1 = *(const float4*)&s_stat[y + 2 + dy][col + 2 + dx][0];
            const float4 n2 = *(const float4*)&s_stat[y + 2 + dy][col + 2 + dx][4];
            float acc = B0 * t1.x * n1.x + B1 * t1.y * n1.y + B2 * t1.z * n1.z;
            float ma  = t2.x * n2.x + t2.y * n2.y + t2.z * n2.z;
            u2.part[dI][y][col] = fmaf(-49.f, ma, acc);
            if (y < 11) {
                B0 += h[0][y + 7] - h[0][y];
                B1 += h[1][y + 7] - h[1][y];
                B2 += h[2][y + 7] - h[2][y];
            }
        }
    }
    __syncthreads();

    // ---- P4: per-pixel cosine accumulation, direct store; 64 thr ----
    if (tid < 64) {
        const int ty = tid >> 3, tx = tid & 7;
        const int gy = y0 + ty, gx = x0 + tx;
        const float rnt = s_rnrm[ty + 2][tx + 2];
        float acc = 0.f, cnt = 0.f;
#pragma unroll
        for (int dI = 0; dI < 12; ++dI) {
            const int u = dI + 13;
            const int dy = u / 5 - 2, dx = u - (u / 5) * 5 - 2;
            if ((unsigned)(gy + dy) < HH && (unsigned)(gx + dx) < WW) {
                acc = fmaf(588.f + u2.part[dI][ty + 2][tx + 2],
                           s_rnrm[ty + 2 + dy][tx + 2 + dx], acc);
                cnt += 1.f;
            }
            if ((unsigned)(gy - dy) < HH && (unsigned)(gx - dx) < WW) {
                acc = fmaf(588.f + u2.part[dI][ty + 2 - dy][tx + 2 - dx],
                           s_rnrm[ty + 2 - dy][tx + 2 - dx], acc);
                cnt += 1.f;
            }
        }
        out[(size_t)blockIdx.z * HH * WW + gy * WW + gx] = 0.5f - acc * rnt / (2.f * cnt);
    }
}

extern "C" void kernel_launch(void* const* d_in, const int* in_sizes, int n_in,
                              void* d_out, int out_size, void* d_ws, size_t ws_size,
                              hipStream_t stream) {
    const float* img = (const float*)d_in[0];
    float* out = (float*)d_out;
    dim3 grid(WW / TX, HH / TY, 2);
    dim3 block(NTHR);
    hipLaunchKernelGGL(err_kernel, grid, block, 0, stream, img, out);
}